// Round 2
// baseline (1876.028 us; speedup 1.0000x reference)
//
#include <hip/hip_runtime.h>
#include <hip/hip_bf16.h>

// TripletGCNModel on MI355X (gfx950), bf16-MFMA implementation.
//
// Shapes: N=20000 nodes, E=100000 edges, DN=DE=256, DH=512, L=2.
// Per layer: GEMM1 (Ex768 @ 768x512, gathered A), GEMM2 (Ex512 @ 512x1280,
// epilogue -> new_e + atomic segment-sum into agg), mean, GEMM3 (Nx512 @
// 512x512), GEMM4 (Nx512 @ 512x256 + residual).
//
// All GEMMs: BM=BN=128, BK=32, 256 threads = 4 waves (2x2), each wave owns a
// 64x64 output subtile = 4x4 fragments of v_mfma_f32_16x16x32_bf16.
// LDS tiles A/B both [128 rows][32 k] bf16 with 16B-chunk XOR swizzle
// (chunk ^= (r ^ r>>2) & 3) applied on BOTH write and read sides.
// Weights transposed to [N][K] bf16 once per launch so B staging == A staging.

typedef __bf16 bf16x8 __attribute__((ext_vector_type(8)));
typedef float f32x4 __attribute__((ext_vector_type(4)));
struct alignas(16) V16 { unsigned int w[4]; };

static constexpr int kN = 20000;
static constexpr int kE = 100000;

__device__ __forceinline__ int swz4(int r) { return (r ^ (r >> 2)) & 3; }

// ---------------- helper kernels ----------------

__global__ void k_count(const int* __restrict__ dstI, float* __restrict__ cnt, int n) {
  int i = blockIdx.x * 256 + threadIdx.x;
  if (i < n) atomicAdd(&cnt[dstI[i]], 1.0f);
}

// Wt[l][n][k] = W[l][k][n], f32 -> bf16. i indexes Wt flat, k fastest.
__global__ void k_cvt_wT(const float* __restrict__ W, __hip_bfloat16* __restrict__ Wt,
                         int Kd, int Nd, int total) {
  int i = blockIdx.x * 256 + threadIdx.x;
  if (i >= total) return;
  int k = i % Kd; int t = i / Kd; int nn = t % Nd; int l = t / Nd;
  Wt[i] = __float2bfloat16(W[((size_t)l * Kd + k) * Nd + nn]);
}

__global__ void k_cvt4(const float* __restrict__ in, __hip_bfloat16* __restrict__ out, int n4) {
  int i = blockIdx.x * 256 + threadIdx.x;
  if (i >= n4) return;
  float4 v = ((const float4*)in)[i];
  out[4 * i + 0] = __float2bfloat16(v.x);
  out[4 * i + 1] = __float2bfloat16(v.y);
  out[4 * i + 2] = __float2bfloat16(v.z);
  out[4 * i + 3] = __float2bfloat16(v.w);
}

// aggb = bf16(agg / max(cnt,1)); agg re-zeroed for the next layer's atomics.
__global__ void k_finalize(float* __restrict__ agg, const float* __restrict__ cnt,
                           __hip_bfloat16* __restrict__ aggb, int total) {
  int i = blockIdx.x * 256 + threadIdx.x;
  if (i >= total) return;
  float c = cnt[i >> 9];  // 512 cols per node
  aggb[i] = __float2bfloat16(agg[i] / fmaxf(c, 1.0f));
  agg[i] = 0.0f;
}

// ---------------- the GEMM ----------------
// MODE 1: A = gather [xb[dst]|eb|xb[src]], out = relu(z) -> outb (bf16, ld=512)
// MODE 2: A = m1, N=1280. cols [0,512): atomicAdd agg[dst][c];
//         [512,768): new_e -> outb(bf16,L0) / outf(f32,last);
//         [768,1280): atomicAdd agg[dst][c-768]. All relu'd.
// MODE 3: A = aggb, out = relu(z) -> outb (bf16, ld=512)
// MODE 4: A = h, z += resid; L0: relu -> outf(f32)+outb(bf16); last: -> outf(f32)
template <int MODE, bool L0>
__global__ __launch_bounds__(256) void gemm_k(
    const __hip_bfloat16* __restrict__ A, const __hip_bfloat16* __restrict__ xb,
    const __hip_bfloat16* __restrict__ eb, const int* __restrict__ srcI,
    const int* __restrict__ dstI, const __hip_bfloat16* __restrict__ Bt,
    const float* __restrict__ bias, int M, int K, int Nld,
    float* __restrict__ agg, __hip_bfloat16* __restrict__ outb,
    float* __restrict__ outf, const float* __restrict__ resid) {
  __shared__ alignas(16) unsigned short smem[8192];  // A: [0,4096) elems, B: [4096,8192)

  const int tid = threadIdx.x;
  const int wave = tid >> 6, lane = tid & 63;
  const int hi = lane >> 4, lo = lane & 15;
  const int wr = wave >> 1, wc = wave & 1;
  const int bm = blockIdx.x, bn = blockIdx.y;

  f32x4 acc[4][4];
#pragma unroll
  for (int a = 0; a < 4; ++a)
#pragma unroll
    for (int b = 0; b < 4; ++b)
#pragma unroll
      for (int i = 0; i < 4; ++i) acc[a][b][i] = 0.0f;

  const int kSteps = K >> 5;
  for (int kt = 0; kt < kSteps; ++kt) {
    // ---- stage 1024 x 16B chunks: A tile then B tile, swizzled slots ----
#pragma unroll
    for (int is = 0; is < 4; ++is) {
      int gc = is * 256 + tid;
      bool isA = (gc < 512);
      int g2 = isA ? gc : gc - 512;
      int r = g2 >> 2, cslot = g2 & 3;
      int col = (kt << 5) + ((cslot ^ swz4(r)) << 3);  // data chunk for this slot
      const __hip_bfloat16* src;
      if (isA) {
        int rg = bm * 128 + r;
        rg = (rg < M) ? rg : (M - 1);
        if (MODE == 1) {
          if (col < 256)      src = xb + (size_t)dstI[rg] * 256 + col;
          else if (col < 512) src = eb + (size_t)rg * 256 + (col - 256);
          else                src = xb + (size_t)srcI[rg] * 256 + (col - 512);
        } else {
          src = A + (size_t)rg * K + col;
        }
      } else {
        src = Bt + (size_t)(bn * 128 + r) * K + col;
      }
      V16 tmp = *(const V16*)src;
      *(V16*)(&smem[(size_t)g2 * 8 + (isA ? 0 : 4096)]) = tmp;
    }
    __syncthreads();

    // ---- fragments + 16 MFMA ----
    bf16x8 af[4], bfr[4];
#pragma unroll
    for (int mi = 0; mi < 4; ++mi) {
      int r = wr * 64 + mi * 16 + lo;
      af[mi] = *(const bf16x8*)(&smem[r * 32 + ((hi ^ swz4(r)) << 3)]);
    }
#pragma unroll
    for (int ni = 0; ni < 4; ++ni) {
      int r = wc * 64 + ni * 16 + lo;
      bfr[ni] = *(const bf16x8*)(&smem[4096 + r * 32 + ((hi ^ swz4(r)) << 3)]);
    }
#pragma unroll
    for (int mi = 0; mi < 4; ++mi)
#pragma unroll
      for (int ni = 0; ni < 4; ++ni)
        acc[mi][ni] = __builtin_amdgcn_mfma_f32_16x16x32_bf16(af[mi], bfr[ni], acc[mi][ni], 0, 0, 0);
    __syncthreads();
  }

  // ---- epilogue: D row = mi*16 + 4*hi + i, col = ni*16 + lo (m89 layout) ----
#pragma unroll
  for (int mi = 0; mi < 4; ++mi) {
    int rowb = bm * 128 + wr * 64 + mi * 16 + 4 * hi;
#pragma unroll
    for (int i = 0; i < 4; ++i) {
      int r = rowb + i;
      if (r >= M) continue;
      int dnode = 0;
      if (MODE == 2) dnode = dstI[r];
#pragma unroll
      for (int ni = 0; ni < 4; ++ni) {
        int col = bn * 128 + wc * 64 + ni * 16 + lo;
        float z = acc[mi][ni][i] + bias[col];
        if (MODE == 1 || MODE == 3) {
          z = fmaxf(z, 0.0f);
          outb[(size_t)r * Nld + col] = __float2bfloat16(z);
        } else if (MODE == 2) {
          z = fmaxf(z, 0.0f);
          if (col < 512) {
            atomicAdd(agg + (size_t)dnode * 512 + col, z);
          } else if (col < 768) {
            int ec = col - 512;
            if (L0) outb[(size_t)r * 256 + ec] = __float2bfloat16(z);
            else    outf[(size_t)r * 256 + ec] = z;
          } else {
            atomicAdd(agg + (size_t)dnode * 512 + (col - 768), z);
          }
        } else {  // MODE 4
          z += resid[(size_t)r * 256 + col];
          if (L0) {
            z = fmaxf(z, 0.0f);
            outf[(size_t)r * 256 + col] = z;
            outb[(size_t)r * 256 + col] = __float2bfloat16(z);
          } else {
            outf[(size_t)r * 256 + col] = z;
          }
        }
      }
    }
  }
}

// ---------------- launch ----------------

extern "C" void kernel_launch(void* const* d_in, const int* in_sizes, int n_in,
                              void* d_out, int out_size, void* d_ws, size_t ws_size,
                              hipStream_t stream) {
  const float* x0  = (const float*)d_in[0];
  const float* e0  = (const float*)d_in[1];
  const int*   idx = (const int*)d_in[2];
  const float* W1a = (const float*)d_in[3];
  const float* b1a = (const float*)d_in[4];
  const float* W1b = (const float*)d_in[5];
  const float* b1b = (const float*)d_in[6];
  const float* W2a = (const float*)d_in[7];
  const float* b2a = (const float*)d_in[8];
  const float* W2b = (const float*)d_in[9];
  const float* b2b = (const float*)d_in[10];
  const int* srcI = idx;
  const int* dstI = idx + kE;
  float* outx = (float*)d_out;                      // N x 256
  float* oute = (float*)d_out + (size_t)kN * 256;   // E x 256

  char* ws = (char*)d_ws;
  size_t off = 0;
  auto alloc = [&](size_t bytes) -> char* {
    char* p = ws + off;
    off += (bytes + 255) & ~(size_t)255;
    return p;
  };
  __hip_bfloat16* W1aT = (__hip_bfloat16*)alloc((size_t)2 * 512 * 768 * 2);
  __hip_bfloat16* W1bT = (__hip_bfloat16*)alloc((size_t)2 * 1280 * 512 * 2);
  __hip_bfloat16* W2aT = (__hip_bfloat16*)alloc((size_t)2 * 512 * 512 * 2);
  __hip_bfloat16* W2bT = (__hip_bfloat16*)alloc((size_t)2 * 256 * 512 * 2);
  __hip_bfloat16* x0b  = (__hip_bfloat16*)alloc((size_t)kN * 256 * 2);
  __hip_bfloat16* x1b  = (__hip_bfloat16*)alloc((size_t)kN * 256 * 2);
  __hip_bfloat16* e0b  = (__hip_bfloat16*)alloc((size_t)kE * 256 * 2);
  __hip_bfloat16* e1b  = (__hip_bfloat16*)alloc((size_t)kE * 256 * 2);
  float*          x1f  = (float*)alloc((size_t)kN * 256 * 4);
  __hip_bfloat16* m1   = (__hip_bfloat16*)alloc((size_t)kE * 512 * 2);
  float*          agg  = (float*)alloc((size_t)kN * 512 * 4);
  __hip_bfloat16* aggb = (__hip_bfloat16*)alloc((size_t)kN * 512 * 2);
  __hip_bfloat16* hbuf = (__hip_bfloat16*)alloc((size_t)kN * 512 * 2);
  float*          cnt  = (float*)alloc((size_t)kN * 4);

  (void)hipMemsetAsync(agg, 0, (size_t)kN * 512 * 4, stream);
  (void)hipMemsetAsync(cnt, 0, (size_t)kN * 4, stream);

  k_count<<<(kE + 255) / 256, 256, 0, stream>>>(dstI, cnt, kE);
  k_cvt_wT<<<(2 * 768 * 512 + 255) / 256, 256, 0, stream>>>(W1a, W1aT, 768, 512, 2 * 768 * 512);
  k_cvt_wT<<<(2 * 512 * 1280 + 255) / 256, 256, 0, stream>>>(W1b, W1bT, 512, 1280, 2 * 512 * 1280);
  k_cvt_wT<<<(2 * 512 * 512 + 255) / 256, 256, 0, stream>>>(W2a, W2aT, 512, 512, 2 * 512 * 512);
  k_cvt_wT<<<(2 * 512 * 256 + 255) / 256, 256, 0, stream>>>(W2b, W2bT, 512, 256, 2 * 512 * 256);
  k_cvt4<<<(kN * 256 / 4 + 255) / 256, 256, 0, stream>>>(x0, x0b, kN * 256 / 4);
  k_cvt4<<<(kE * 256 / 4 + 255) / 256, 256, 0, stream>>>(e0, e0b, kE * 256 / 4);

  dim3 blk(256);
  int gmE = (kE + 127) / 128;  // 782
  int gmN = (kN + 127) / 128;  // 157

  // ---- layer 0 ----
  gemm_k<1, true><<<dim3(gmE, 4), blk, 0, stream>>>(
      nullptr, x0b, e0b, srcI, dstI, W1aT, b1a, kE, 768, 512, nullptr, m1, nullptr, nullptr);
  gemm_k<2, true><<<dim3(gmE, 10), blk, 0, stream>>>(
      m1, nullptr, nullptr, srcI, dstI, W1bT, b1b, kE, 512, 1280, agg, e1b, nullptr, nullptr);
  k_finalize<<<(kN * 512 + 255) / 256, 256, 0, stream>>>(agg, cnt, aggb, kN * 512);
  gemm_k<3, true><<<dim3(gmN, 4), blk, 0, stream>>>(
      aggb, nullptr, nullptr, srcI, dstI, W2aT, b2a, kN, 512, 512, nullptr, hbuf, nullptr, nullptr);
  gemm_k<4, true><<<dim3(gmN, 2), blk, 0, stream>>>(
      hbuf, nullptr, nullptr, srcI, dstI, W2bT, b2b, kN, 512, 256, nullptr, x1b, x1f, x0);

  // ---- layer 1 (last) ----
  gemm_k<1, false><<<dim3(gmE, 4), blk, 0, stream>>>(
      nullptr, x1b, e1b, srcI, dstI, W1aT + (size_t)512 * 768, b1a + 512, kE, 768, 512,
      nullptr, m1, nullptr, nullptr);
  gemm_k<2, false><<<dim3(gmE, 10), blk, 0, stream>>>(
      m1, nullptr, nullptr, srcI, dstI, W1bT + (size_t)1280 * 512, b1b + 1280, kE, 512, 1280,
      agg, nullptr, oute, nullptr);
  k_finalize<<<(kN * 512 + 255) / 256, 256, 0, stream>>>(agg, cnt, aggb, kN * 512);
  gemm_k<3, false><<<dim3(gmN, 4), blk, 0, stream>>>(
      aggb, nullptr, nullptr, srcI, dstI, W2aT + (size_t)512 * 512, b2a + 512, kN, 512, 512,
      nullptr, hbuf, nullptr, nullptr);
  gemm_k<4, false><<<dim3(gmN, 2), blk, 0, stream>>>(
      hbuf, nullptr, nullptr, srcI, dstI, W2bT + (size_t)256 * 512, b2b + 256, kN, 512, 256,
      nullptr, nullptr, outx, x1f);
}